// Round 2
// baseline (3844.938 us; speedup 1.0000x reference)
//
#include <hip/hip_runtime.h>

// Problem constants (from reference): z [16,64,4096] f32, codebooks [8,1024,64] f32
#define S      8        // number of codebooks (stages)
#define K      1024     // codewords per codebook
#define D      64       // code dim
#define TDIM   4096     // T
#define NVEC   65536    // B*T = 16*4096
#define VPB    64       // vectors per block (= lanes per wave)
#define NBLK   (NVEC / VPB)   // 1024 blocks
#define KPW    (K / 4)        // 256 codewords per wave (4 waves/block)
#define NELEM  4194304.0f     // B*T*D
#define EPSQ   1e-10f

// ---------------------------------------------------------------------------
// Prep: c2[s*K+k] = ||codebook[s][k]||^2 ; zero loss accumulators + histogram
// ---------------------------------------------------------------------------
__global__ void rvq_prep(const float* __restrict__ cb, float* __restrict__ c2,
                         float* __restrict__ loss_ws, unsigned* __restrict__ cnt) {
    int i = blockIdx.x * blockDim.x + threadIdx.x;  // 0..8191
    if (i < S * K) {
        const float* row = cb + i * D;
        float s0 = 0.f, s1 = 0.f, s2 = 0.f, s3 = 0.f;
#pragma unroll
        for (int d = 0; d < D; d += 4) {
            s0 = fmaf(row[d + 0], row[d + 0], s0);
            s1 = fmaf(row[d + 1], row[d + 1], s1);
            s2 = fmaf(row[d + 2], row[d + 2], s2);
            s3 = fmaf(row[d + 3], row[d + 3], s3);
        }
        c2[i] = (s0 + s1) + (s2 + s3);
        cnt[i] = 0u;
        if (i < S) loss_ws[i] = 0.0f;
    }
}

// ---------------------------------------------------------------------------
// Main: one lane per vector; 4 waves/block each scan a disjoint k-quarter
// (wave-uniform codeword address -> scalar loads). Cross-wave argmin via LDS.
// residual_final gives zq = z - r and loss_s = sum(r_{s+1}^2).
// ---------------------------------------------------------------------------
__global__ __launch_bounds__(256, 4)
void rvq_main(const float* __restrict__ z, const float* __restrict__ cb,
              const float* __restrict__ c2, float* __restrict__ zq,
              float* __restrict__ loss_ws, unsigned* __restrict__ cnt) {
    __shared__ float lds_d[S][4][VPB];
    __shared__ int   lds_k[S][4][VPB];

    const int lane = threadIdx.x & 63;
    const int wave = threadIdx.x >> 6;
    const int vec  = blockIdx.x * VPB + lane;       // 64 consecutive t within one b
    const int b    = vec >> 12;                     // vec / 4096
    const int t    = vec & 4095;

    const float* zbase = z + (((size_t)(b * D)) << 12) + t;  // z[b][d][t] = zbase[d<<12]

    float r[D];
#pragma unroll
    for (int d = 0; d < D; ++d) r[d] = zbase[((size_t)d) << 12];

    for (int s = 0; s < S; ++s) {
        const float* cbs = cb + s * (K * D);
        const float* c2s = c2 + s * K;

        // --- argmin over this wave's k-quarter (wave-uniform codeword addr) ---
        float bestd = 3.4e38f;
        int   bestk = 0;
        const int kbeg = wave * KPW;
        const int kend = kbeg + KPW;
        for (int k = kbeg; k < kend; ++k) {
            const float* cw = cbs + k * D;   // uniform across the wave -> s_load
            float a0 = 0.f, a1 = 0.f, a2 = 0.f, a3 = 0.f;
#pragma unroll
            for (int d = 0; d < D; d += 4) {
                a0 = fmaf(r[d + 0], cw[d + 0], a0);
                a1 = fmaf(r[d + 1], cw[d + 1], a1);
                a2 = fmaf(r[d + 2], cw[d + 2], a2);
                a3 = fmaf(r[d + 3], cw[d + 3], a3);
            }
            float score = c2s[k] - 2.0f * ((a0 + a1) + (a2 + a3));
            if (score < bestd) { bestd = score; bestk = k; }  // strict < : first-min tie-break
        }

        // --- cross-wave argmin (per-stage LDS slot -> single barrier/stage) ---
        lds_d[s][wave][lane] = bestd;
        lds_k[s][wave][lane] = bestk;
        __syncthreads();
        float bd = lds_d[s][0][lane];
        int   bk = lds_k[s][0][lane];
#pragma unroll
        for (int w = 1; w < 4; ++w) {
            float dd = lds_d[s][w][lane];
            int   kk = lds_k[s][w][lane];
            if (dd < bd) { bd = dd; bk = kk; }   // lower wave = lower k wins ties
        }

        // --- residual update (per-lane gather of the chosen codeword) ---
        const float* qw = cbs + bk * D;
#pragma unroll
        for (int d = 0; d < D; ++d) r[d] -= qw[d];

        // --- loss + histogram (wave 0 only; all waves hold identical r) ---
        if (wave == 0) {
            float ls = 0.f;
#pragma unroll
            for (int d = 0; d < D; ++d) ls = fmaf(r[d], r[d], ls);
#pragma unroll
            for (int off = 32; off > 0; off >>= 1) ls += __shfl_down(ls, off);
            if (lane == 0) atomicAdd(&loss_ws[s], ls);
            atomicAdd(&cnt[s * K + bk], 1u);
        }
    }

    // --- epilogue: zq = z - r_final (coalesced over t) ---
    if (wave == 0) {
        float* zqbase = zq + (((size_t)(b * D)) << 12) + t;
#pragma unroll
        for (int d = 0; d < D; ++d)
            zqbase[((size_t)d) << 12] = zbase[((size_t)d) << 12] - r[d];
    }
}

// ---------------------------------------------------------------------------
// Finalize: losses (mean) + perplexities (exp(-sum p ln(p+eps)))
// ---------------------------------------------------------------------------
__global__ void rvq_finalize(const float* __restrict__ loss_ws,
                             const unsigned* __restrict__ cnt,
                             float* __restrict__ out_loss,
                             float* __restrict__ out_perp) {
    const int s   = blockIdx.x;     // 8 blocks
    const int tid = threadIdx.x;    // 256 threads
    float partial = 0.f;
    for (int i = tid; i < K; i += 256) {
        float p = (float)cnt[s * K + i] * (1.0f / 65536.0f);
        partial += p * logf(p + EPSQ);
    }
    __shared__ float red[4];
#pragma unroll
    for (int off = 32; off > 0; off >>= 1) partial += __shfl_down(partial, off);
    if ((tid & 63) == 0) red[tid >> 6] = partial;
    __syncthreads();
    if (tid == 0) {
        float tot = red[0] + red[1] + red[2] + red[3];
        out_perp[s] = expf(-tot);
        out_loss[s] = loss_ws[s] * (1.0f / NELEM);
    }
}

// ---------------------------------------------------------------------------
extern "C" void kernel_launch(void* const* d_in, const int* in_sizes, int n_in,
                              void* d_out, int out_size, void* d_ws, size_t ws_size,
                              hipStream_t stream) {
    const float* z  = (const float*)d_in[0];   // [16,64,4096]
    const float* cb = (const float*)d_in[1];   // [8,1024,64]

    float* zq       = (float*)d_out;           // 4194304
    float* out_loss = zq + 4194304;            // 8
    float* out_perp = out_loss + 8;            // 8

    float*    c2      = (float*)d_ws;          // 8192 floats
    float*    loss_ws = c2 + S * K;            // 8 floats
    unsigned* cnt     = (unsigned*)(loss_ws + S); // 8192 uints

    hipLaunchKernelGGL(rvq_prep,     dim3(32),   dim3(256), 0, stream, cb, c2, loss_ws, cnt);
    hipLaunchKernelGGL(rvq_main,     dim3(NBLK), dim3(256), 0, stream, z, cb, c2, zq, loss_ws, cnt);
    hipLaunchKernelGGL(rvq_finalize, dim3(S),    dim3(256), 0, stream, loss_ws, cnt, out_loss, out_perp);
}

// Round 3
// 1815.041 us; speedup vs baseline: 2.1184x; 2.1184x over previous
//
#include <hip/hip_runtime.h>

// Problem constants (from reference): z [16,64,4096] f32, codebooks [8,1024,64] f32
#define S      8        // number of codebooks (stages)
#define K      1024     // codewords per codebook
#define D      64       // code dim
#define NVEC   65536    // B*T = 16*4096
#define VPB    64       // vectors per block (= lanes per wave)
#define NBLK   (NVEC / VPB)   // 1024 blocks
#define KPW    (K / 4)        // 256 codewords per wave (4 waves/block)
#define NELEM  4194304.0f     // B*T*D
#define EPSQ   1e-10f

// ---------------------------------------------------------------------------
// Prep: c2[s*K+k] = ||codebook[s][k]||^2 ; zero loss accumulators + histogram
// ---------------------------------------------------------------------------
__global__ void rvq_prep(const float* __restrict__ cb, float* __restrict__ c2,
                         float* __restrict__ loss_ws, unsigned* __restrict__ cnt) {
    int i = blockIdx.x * blockDim.x + threadIdx.x;  // 0..8191
    if (i < S * K) {
        const float* row = cb + i * D;
        float s0 = 0.f, s1 = 0.f, s2 = 0.f, s3 = 0.f;
#pragma unroll
        for (int d = 0; d < D; d += 4) {
            s0 = fmaf(row[d + 0], row[d + 0], s0);
            s1 = fmaf(row[d + 1], row[d + 1], s1);
            s2 = fmaf(row[d + 2], row[d + 2], s2);
            s3 = fmaf(row[d + 3], row[d + 3], s3);
        }
        c2[i] = (s0 + s1) + (s2 + s3);
        cnt[i] = 0u;
        if (i < S) loss_ws[i] = 0.0f;
    }
}

// ---------------------------------------------------------------------------
// Main: one lane per vector; 4 waves/block each scan a disjoint k-quarter.
// Codeword addresses are forced wave-uniform via readfirstlane -> the
// compiler emits s_load for the codebook; inner loop is v_fma_f32 with one
// SGPR operand. r[64] stays in VGPRs (~90 total, under the 128 cap).
// ---------------------------------------------------------------------------
__global__ __launch_bounds__(256, 4)
void rvq_main(const float* __restrict__ z, const float* __restrict__ cb,
              const float* __restrict__ c2, float* __restrict__ zq,
              float* __restrict__ loss_ws, unsigned* __restrict__ cnt) {
    __shared__ float lds_d[S][4][VPB];
    __shared__ int   lds_k[S][4][VPB];

    const int lane = threadIdx.x & 63;
    const int wave = threadIdx.x >> 6;
    const int vec  = blockIdx.x * VPB + lane;       // 64 consecutive t within one b
    const int b    = vec >> 12;                     // vec / 4096
    const int t    = vec & 4095;

    // Force wave-uniform k-range into SGPRs so codeword loads scalarize.
    const int kbeg = __builtin_amdgcn_readfirstlane(wave * KPW);

    const float* zbase = z + (((size_t)(b * D)) << 12) + t;  // z[b][d][t] = zbase[d<<12]

    float r[D];
#pragma unroll
    for (int d = 0; d < D; ++d) r[d] = zbase[((size_t)d) << 12];

    for (int s = 0; s < S; ++s) {
        const float* cbs = cb + s * (K * D);
        // wave-uniform bases (kbeg is SGPR, s is uniform)
        const float* cw0 = cbs + (size_t)kbeg * D;
        const float* c20 = c2 + s * K + kbeg;

        // --- argmin over this wave's k-quarter (scalar codeword loads) ---
        float bestd = 3.4e38f;
        int   bestk = 0;
        for (int kk = 0; kk < KPW; ++kk) {
            const float* cw = cw0 + kk * D;   // uniform -> s_load_dwordx16
            float a0 = 0.f, a1 = 0.f, a2 = 0.f, a3 = 0.f;
#pragma unroll
            for (int d = 0; d < D; d += 4) {
                a0 = fmaf(r[d + 0], cw[d + 0], a0);
                a1 = fmaf(r[d + 1], cw[d + 1], a1);
                a2 = fmaf(r[d + 2], cw[d + 2], a2);
                a3 = fmaf(r[d + 3], cw[d + 3], a3);
            }
            float score = c20[kk] - 2.0f * ((a0 + a1) + (a2 + a3));
            // branchless, strict < : first (lowest k) minimum wins ties
            bestk = (score < bestd) ? (kbeg + kk) : bestk;
            bestd = fminf(score, bestd);
        }

        // --- cross-wave argmin (per-stage LDS slot -> single barrier/stage) ---
        lds_d[s][wave][lane] = bestd;
        lds_k[s][wave][lane] = bestk;
        __syncthreads();
        float bd = lds_d[s][0][lane];
        int   bk = lds_k[s][0][lane];
#pragma unroll
        for (int w = 1; w < 4; ++w) {
            float dd = lds_d[s][w][lane];
            int   kk = lds_k[s][w][lane];
            bk = (dd < bd) ? kk : bk;   // lower wave = lower k wins ties
            bd = fminf(dd, bd);
        }

        // --- residual update (per-lane gather of the chosen codeword) ---
        const float* qw = cbs + (size_t)bk * D;
#pragma unroll
        for (int d = 0; d < D; ++d) r[d] -= qw[d];

        // --- loss + histogram (wave 0 only; all waves hold identical r) ---
        if (wave == 0) {
            float ls = 0.f;
#pragma unroll
            for (int d = 0; d < D; ++d) ls = fmaf(r[d], r[d], ls);
#pragma unroll
            for (int off = 32; off > 0; off >>= 1) ls += __shfl_down(ls, off);
            if (lane == 0) atomicAdd(&loss_ws[s], ls);
            atomicAdd(&cnt[s * K + bk], 1u);
        }
    }

    // --- epilogue: zq = z - r_final (coalesced over t) ---
    if (wave == 0) {
        float* zqbase = zq + (((size_t)(b * D)) << 12) + t;
#pragma unroll
        for (int d = 0; d < D; ++d)
            zqbase[((size_t)d) << 12] = zbase[((size_t)d) << 12] - r[d];
    }
}

// ---------------------------------------------------------------------------
// Finalize: losses (mean) + perplexities (exp(-sum p ln(p+eps)))
// ---------------------------------------------------------------------------
__global__ void rvq_finalize(const float* __restrict__ loss_ws,
                             const unsigned* __restrict__ cnt,
                             float* __restrict__ out_loss,
                             float* __restrict__ out_perp) {
    const int s   = blockIdx.x;     // 8 blocks
    const int tid = threadIdx.x;    // 256 threads
    float partial = 0.f;
    for (int i = tid; i < K; i += 256) {
        float p = (float)cnt[s * K + i] * (1.0f / 65536.0f);
        partial += p * logf(p + EPSQ);
    }
    __shared__ float red[4];
#pragma unroll
    for (int off = 32; off > 0; off >>= 1) partial += __shfl_down(partial, off);
    if ((tid & 63) == 0) red[tid >> 6] = partial;
    __syncthreads();
    if (tid == 0) {
        float tot = red[0] + red[1] + red[2] + red[3];
        out_perp[s] = expf(-tot);
        out_loss[s] = loss_ws[s] * (1.0f / NELEM);
    }
}

// ---------------------------------------------------------------------------
extern "C" void kernel_launch(void* const* d_in, const int* in_sizes, int n_in,
                              void* d_out, int out_size, void* d_ws, size_t ws_size,
                              hipStream_t stream) {
    const float* z  = (const float*)d_in[0];   // [16,64,4096]
    const float* cb = (const float*)d_in[1];   // [8,1024,64]

    float* zq       = (float*)d_out;           // 4194304
    float* out_loss = zq + 4194304;            // 8
    float* out_perp = out_loss + 8;            // 8

    float*    c2      = (float*)d_ws;          // 8192 floats
    float*    loss_ws = c2 + S * K;            // 8 floats
    unsigned* cnt     = (unsigned*)(loss_ws + S); // 8192 uints

    hipLaunchKernelGGL(rvq_prep,     dim3(32),   dim3(256), 0, stream, cb, c2, loss_ws, cnt);
    hipLaunchKernelGGL(rvq_main,     dim3(NBLK), dim3(256), 0, stream, z, cb, c2, zq, loss_ws, cnt);
    hipLaunchKernelGGL(rvq_finalize, dim3(S),    dim3(256), 0, stream, loss_ws, cnt, out_loss, out_perp);
}

// Round 4
// 1800.025 us; speedup vs baseline: 2.1360x; 1.0083x over previous
//
#include <hip/hip_runtime.h>

// Problem constants (from reference): z [16,64,4096] f32, codebooks [8,1024,64] f32
#define S      8        // number of codebooks (stages)
#define K      1024     // codewords per codebook
#define D      64       // code dim
#define NVEC   65536    // B*T = 16*4096
#define VPB    64       // vectors per block (= lanes per wave)
#define NBLK   (NVEC / VPB)   // 1024 blocks
#define KPW    (K / 4)        // 256 codewords per wave (4 waves/block)
#define NELEM  4194304.0f     // B*T*D
#define EPSQ   1e-10f

// ---------------------------------------------------------------------------
// Prep: c2[s*K+k] = ||codebook[s][k]||^2 ; zero loss accumulators + histogram
// ---------------------------------------------------------------------------
__global__ void rvq_prep(const float* __restrict__ cb, float* __restrict__ c2,
                         float* __restrict__ loss_ws, unsigned* __restrict__ cnt) {
    int i = blockIdx.x * blockDim.x + threadIdx.x;  // 0..8191
    if (i < S * K) {
        const float* row = cb + i * D;
        float s0 = 0.f, s1 = 0.f, s2 = 0.f, s3 = 0.f;
#pragma unroll
        for (int d = 0; d < D; d += 4) {
            s0 = fmaf(row[d + 0], row[d + 0], s0);
            s1 = fmaf(row[d + 1], row[d + 1], s1);
            s2 = fmaf(row[d + 2], row[d + 2], s2);
            s3 = fmaf(row[d + 3], row[d + 3], s3);
        }
        c2[i] = (s0 + s1) + (s2 + s3);
        cnt[i] = 0u;
        if (i < S) loss_ws[i] = 0.0f;
    }
}

// ---------------------------------------------------------------------------
// Main: one lane per vector; 4 waves/block each scan a disjoint k-quarter.
// Codeword addresses forced wave-uniform via readfirstlane -> s_load (SGPR
// broadcast, no VGPR cost). The residual-update gather is chunked with
// sched_barrier(0) so only 16 load results are in flight at once — keeps
// r[64] + temps under the 128-VGPR cap (the R3 spill source: a 64-wide
// load burst while r[] was live).
// ---------------------------------------------------------------------------
__global__ __launch_bounds__(256, 4)
void rvq_main(const float* __restrict__ z, const float* __restrict__ cb,
              const float* __restrict__ c2, float* __restrict__ zq,
              float* __restrict__ loss_ws, unsigned* __restrict__ cnt) {
    __shared__ float lds_d[S][4][VPB];
    __shared__ int   lds_k[S][4][VPB];

    const int lane = threadIdx.x & 63;
    const int wave = threadIdx.x >> 6;
    const int vec  = blockIdx.x * VPB + lane;       // 64 consecutive t within one b
    const int b    = vec >> 12;                     // vec / 4096
    const int t    = vec & 4095;

    // Force wave-uniform k-range into SGPRs so codeword loads scalarize.
    const int kbeg = __builtin_amdgcn_readfirstlane(wave * KPW);

    const float* zbase = z + (((size_t)(b * D)) << 12) + t;  // z[b][d][t] = zbase[d<<12]

    float r[D];
#pragma unroll
    for (int d = 0; d < D; ++d) r[d] = zbase[((size_t)d) << 12];

    for (int s = 0; s < S; ++s) {
        const float* cbs = cb + s * (K * D);
        // wave-uniform bases (kbeg is SGPR, s is uniform)
        const float* cw0 = cbs + (size_t)kbeg * D;
        const float* c20 = c2 + s * K + kbeg;

        // --- argmin over this wave's k-quarter (scalar codeword loads) ---
        float bestd = 3.4e38f;
        int   bestk = 0;
        for (int kk = 0; kk < KPW; ++kk) {
            const float* cw = cw0 + kk * D;   // uniform -> s_load_dwordx16
            float a0 = 0.f, a1 = 0.f, a2 = 0.f, a3 = 0.f;
#pragma unroll
            for (int d = 0; d < D; d += 4) {
                a0 = fmaf(r[d + 0], cw[d + 0], a0);
                a1 = fmaf(r[d + 1], cw[d + 1], a1);
                a2 = fmaf(r[d + 2], cw[d + 2], a2);
                a3 = fmaf(r[d + 3], cw[d + 3], a3);
            }
            float score = c20[kk] - 2.0f * ((a0 + a1) + (a2 + a3));
            // branchless, strict < : first (lowest k) minimum wins ties
            bestk = (score < bestd) ? (kbeg + kk) : bestk;
            bestd = fminf(score, bestd);
        }

        // --- cross-wave argmin (per-stage LDS slot -> single barrier/stage) ---
        lds_d[s][wave][lane] = bestd;
        lds_k[s][wave][lane] = bestk;
        __syncthreads();
        float bd = lds_d[s][0][lane];
        int   bk = lds_k[s][0][lane];
#pragma unroll
        for (int w = 1; w < 4; ++w) {
            float dd = lds_d[s][w][lane];
            int   kk = lds_k[s][w][lane];
            bk = (dd < bd) ? kk : bk;   // lower wave = lower k wins ties
            bd = fminf(dd, bd);
        }

        // --- residual update: chunked gather, max 16 load results in flight ---
        const float* qw = cbs + (size_t)bk * D;
#pragma unroll
        for (int c = 0; c < D; c += 16) {
            float4 q0 = *reinterpret_cast<const float4*>(qw + c + 0);
            float4 q1 = *reinterpret_cast<const float4*>(qw + c + 4);
            float4 q2 = *reinterpret_cast<const float4*>(qw + c + 8);
            float4 q3 = *reinterpret_cast<const float4*>(qw + c + 12);
            r[c +  0] -= q0.x; r[c +  1] -= q0.y; r[c +  2] -= q0.z; r[c +  3] -= q0.w;
            r[c +  4] -= q1.x; r[c +  5] -= q1.y; r[c +  6] -= q1.z; r[c +  7] -= q1.w;
            r[c +  8] -= q2.x; r[c +  9] -= q2.y; r[c + 10] -= q2.z; r[c + 11] -= q2.w;
            r[c + 12] -= q3.x; r[c + 13] -= q3.y; r[c + 14] -= q3.z; r[c + 15] -= q3.w;
            __builtin_amdgcn_sched_barrier(0);   // cap the load burst (anti-spill)
        }

        // --- loss + histogram (wave 0 only; all waves hold identical r) ---
        if (wave == 0) {
            float ls = 0.f;
#pragma unroll
            for (int d = 0; d < D; ++d) ls = fmaf(r[d], r[d], ls);
#pragma unroll
            for (int off = 32; off > 0; off >>= 1) ls += __shfl_down(ls, off);
            if (lane == 0) atomicAdd(&loss_ws[s], ls);
            atomicAdd(&cnt[s * K + bk], 1u);
        }
    }

    // --- epilogue: zq = z - r_final (coalesced over t), chunked like the gather ---
    if (wave == 0) {
        float* zqbase = zq + (((size_t)(b * D)) << 12) + t;
#pragma unroll
        for (int c = 0; c < D; c += 8) {
            float z0 = zbase[((size_t)(c + 0)) << 12];
            float z1 = zbase[((size_t)(c + 1)) << 12];
            float z2 = zbase[((size_t)(c + 2)) << 12];
            float z3 = zbase[((size_t)(c + 3)) << 12];
            float z4 = zbase[((size_t)(c + 4)) << 12];
            float z5 = zbase[((size_t)(c + 5)) << 12];
            float z6 = zbase[((size_t)(c + 6)) << 12];
            float z7 = zbase[((size_t)(c + 7)) << 12];
            zqbase[((size_t)(c + 0)) << 12] = z0 - r[c + 0];
            zqbase[((size_t)(c + 1)) << 12] = z1 - r[c + 1];
            zqbase[((size_t)(c + 2)) << 12] = z2 - r[c + 2];
            zqbase[((size_t)(c + 3)) << 12] = z3 - r[c + 3];
            zqbase[((size_t)(c + 4)) << 12] = z4 - r[c + 4];
            zqbase[((size_t)(c + 5)) << 12] = z5 - r[c + 5];
            zqbase[((size_t)(c + 6)) << 12] = z6 - r[c + 6];
            zqbase[((size_t)(c + 7)) << 12] = z7 - r[c + 7];
            __builtin_amdgcn_sched_barrier(0);   // cap the load burst (anti-spill)
        }
    }
}

// ---------------------------------------------------------------------------
// Finalize: losses (mean) + perplexities (exp(-sum p ln(p+eps)))
// ---------------------------------------------------------------------------
__global__ void rvq_finalize(const float* __restrict__ loss_ws,
                             const unsigned* __restrict__ cnt,
                             float* __restrict__ out_loss,
                             float* __restrict__ out_perp) {
    const int s   = blockIdx.x;     // 8 blocks
    const int tid = threadIdx.x;    // 256 threads
    float partial = 0.f;
    for (int i = tid; i < K; i += 256) {
        float p = (float)cnt[s * K + i] * (1.0f / 65536.0f);
        partial += p * logf(p + EPSQ);
    }
    __shared__ float red[4];
#pragma unroll
    for (int off = 32; off > 0; off >>= 1) partial += __shfl_down(partial, off);
    if ((tid & 63) == 0) red[tid >> 6] = partial;
    __syncthreads();
    if (tid == 0) {
        float tot = red[0] + red[1] + red[2] + red[3];
        out_perp[s] = expf(-tot);
        out_loss[s] = loss_ws[s] * (1.0f / NELEM);
    }
}

// ---------------------------------------------------------------------------
extern "C" void kernel_launch(void* const* d_in, const int* in_sizes, int n_in,
                              void* d_out, int out_size, void* d_ws, size_t ws_size,
                              hipStream_t stream) {
    const float* z  = (const float*)d_in[0];   // [16,64,4096]
    const float* cb = (const float*)d_in[1];   // [8,1024,64]

    float* zq       = (float*)d_out;           // 4194304
    float* out_loss = zq + 4194304;            // 8
    float* out_perp = out_loss + 8;            // 8

    float*    c2      = (float*)d_ws;          // 8192 floats
    float*    loss_ws = c2 + S * K;            // 8 floats
    unsigned* cnt     = (unsigned*)(loss_ws + S); // 8192 uints

    hipLaunchKernelGGL(rvq_prep,     dim3(32),   dim3(256), 0, stream, cb, c2, loss_ws, cnt);
    hipLaunchKernelGGL(rvq_main,     dim3(NBLK), dim3(256), 0, stream, z, cb, c2, zq, loss_ws, cnt);
    hipLaunchKernelGGL(rvq_finalize, dim3(S),    dim3(256), 0, stream, loss_ws, cnt, out_loss, out_perp);
}